// Round 10
// baseline (249.994 us; speedup 1.0000x reference)
//
#include <hip/hip_runtime.h>

// out[b,s,o] = sum_i x[b,s,i] * qw[o,i],  qw = ternary(W, 0.3)
// W ~ N(0, 0.1^2) => ~0.27% nonzeros (~1.4 per output column).
// Sparse signed gather-add. R9 lesson: per-lane predicated 12-slot unrolled
// loop issued 192 ds_reads/thread/tile -> LDS-issue-bound at 99us.
// R10: sort columns by count + wave-uniform early-exit loop -> ~20 issued
// slots per block instead of 96; LDS-bounce restores coalesced stores.

#define TH    0.3f
#define NSLOT 16      // register-held entries per column (P(cnt>16) ~ 1e-15)
#define ROWS  16      // x rows per tile (32 KB LDS)
#define HALF  8       // rows per accumulator pass (keeps VGPR < 64)
#define KDIM  512
#define NDIM  512

// ---------------- Kernel 1a: per-column entry lists (unsorted) ----------------
// grid = 512 blocks (one per output column = W row), 64 threads, coalesced row scan.
__global__ __launch_bounds__(64) void build_tbl(const float* __restrict__ w,
                                                int* __restrict__ counts,
                                                int* __restrict__ tbl) {
    const int o    = blockIdx.x;
    const int lane = threadIdx.x;
    __shared__ int c;
    __shared__ int se[KDIM];
    if (lane == 0) c = 0;
    __syncthreads();
    const float* row = w + (size_t)o * KDIM;
    for (int i = lane; i < KDIM; i += 64) {
        float v = row[i];
        if (v > TH || v < -TH) {                 // strict, matches reference
            int pos = atomicAdd(&c, 1);
            se[pos] = (i << 1) | (v < 0.0f ? 1 : 0);
        }
    }
    __syncthreads();
    const int cnt = c;
    if (lane == 0) counts[o] = cnt;
    for (int k = lane; k < NSLOT; k += 64)
        tbl[o * NSLOT + k] = (k < cnt) ? se[k] : 0;
}

// ---------------- Kernel 1b: counting-sort columns by cnt (descending) --------
// 1 block, 512 threads. Produces perm/scnt/stbl in sorted order.
__global__ __launch_bounds__(512) void sort_cols(const int* __restrict__ counts,
                                                 const int* __restrict__ tbl,
                                                 int* __restrict__ perm,
                                                 int* __restrict__ scnt,
                                                 int* __restrict__ stbl) {
    const int t = threadIdx.x;
    const int cnt = counts[t];
    const int key = cnt < (NSLOT + 1) ? cnt : (NSLOT + 1);   // cap key
    __shared__ int base[NSLOT + 2];
    if (t < NSLOT + 2) base[t] = 0;
    __syncthreads();
    atomicAdd(&base[key], 1);
    __syncthreads();
    if (t == 0) {                       // descending exclusive scan
        int run = 0;
        for (int c2 = NSLOT + 1; c2 >= 0; --c2) { int h = base[c2]; base[c2] = run; run += h; }
    }
    __syncthreads();
    const int pos = atomicAdd(&base[key], 1);
    perm[pos] = t;
    scnt[pos] = cnt;
#pragma unroll
    for (int k = 0; k < NSLOT; ++k) stbl[pos * NSLOT + k] = tbl[t * NSLOT + k];
}

// ---------------- Kernel 2: streaming sparse gather-add ----------------
__global__ __launch_bounds__(512, 8) void ternary_mm(
        const float* __restrict__ x, const float* __restrict__ w,
        const int* __restrict__ perm, const int* __restrict__ scnt,
        const int* __restrict__ stbl, float* __restrict__ out, int ntiles) {
    __shared__ float xs[ROWS * KDIM];            // 32 KB, doubles as out-bounce

    const int t  = threadIdx.x;
    const int c  = perm[t];                      // my output column
    const int ct = scnt[t];
    int e[NSLOT];
#pragma unroll
    for (int k = 0; k < NSLOT; ++k) e[k] = stbl[t * NSLOT + k];

    const int fast = (ct <= NSLOT) ? ct : 0;     // fallback lanes excluded
    int wm = fast;                               // wave-max of fast counts
#pragma unroll
    for (int off = 32; off; off >>= 1) { int o2 = __shfl_xor(wm, off); wm = wm > o2 ? wm : o2; }
    wm = __builtin_amdgcn_readfirstlane(wm);     // scalar loop bound

    for (int tile = blockIdx.x; tile < ntiles; tile += gridDim.x) {
        const size_t base = (size_t)tile * (ROWS * KDIM);

        __syncthreads();                         // prev tile's stores read xs
        {
            const float4* src = (const float4*)(x + base);
            float4 st0 = src[0 * 512 + t];
            float4 st1 = src[1 * 512 + t];
            float4 st2 = src[2 * 512 + t];
            float4 st3 = src[3 * 512 + t];
            float4* dst = (float4*)xs;
            dst[0 * 512 + t] = st0;
            dst[1 * 512 + t] = st1;
            dst[2 * 512 + t] = st2;
            dst[3 * 512 + t] = st3;
        }
        __syncthreads();                         // tile staged

#pragma unroll
        for (int h = 0; h < 2; ++h) {
            float acc[HALF];
#pragma unroll
            for (int r = 0; r < HALF; ++r) acc[r] = 0.0f;

            if (ct <= NSLOT) {
#pragma unroll
                for (int k = 0; k < NSLOT; ++k) {
                    if (k >= wm) break;          // uniform: skips issue
                    if (k < fast) {              // per-lane
                        const int ent  = e[k];
                        const int idx  = ent >> 1;
                        const int smsk = (ent & 1) << 31;
#pragma unroll
                        for (int r = 0; r < HALF; ++r) {
                            float v = xs[(h * HALF + r) * KDIM + idx];
                            acc[r] += __int_as_float(__float_as_int(v) ^ smsk);
                        }
                    }
                }
            } else {
                // parachute: rescan weight row from global (P ~ 1e-15)
                const float* wrow = w + (size_t)c * KDIM;
                for (int i = 0; i < KDIM; ++i) {
                    float wv = wrow[i];
                    if (wv > TH || wv < -TH) {
                        const int smsk = (wv < 0.0f) ? (1 << 31) : 0;
#pragma unroll
                        for (int r = 0; r < HALF; ++r) {
                            float v = xs[(h * HALF + r) * KDIM + i];
                            acc[r] += __int_as_float(__float_as_int(v) ^ smsk);
                        }
                    }
                }
            }

            __syncthreads();                     // all reads of this half done
#pragma unroll
            for (int r = 0; r < HALF; ++r)       // bounce: scatter by column
                xs[(h * HALF + r) * KDIM + c] = acc[r];
            // no barrier needed before next half: disjoint row regions
        }
        __syncthreads();                         // bounce writes visible

        {
            float4* dst = (float4*)(out + base); // coalesced stores
            const float4* s4 = (const float4*)xs;
            dst[0 * 512 + t] = s4[0 * 512 + t];
            dst[1 * 512 + t] = s4[1 * 512 + t];
            dst[2 * 512 + t] = s4[2 * 512 + t];
            dst[3 * 512 + t] = s4[3 * 512 + t];
        }
    }
}

extern "C" void kernel_launch(void* const* d_in, const int* in_sizes, int n_in,
                              void* d_out, int out_size, void* d_ws, size_t ws_size,
                              hipStream_t stream) {
    const float* x = (const float*)d_in[0];   // [16,4096,512] f32
    const float* w = (const float*)d_in[1];   // [512,512] f32
    float* out = (float*)d_out;               // [16,4096,512] f32

    int* counts = (int*)d_ws;                     // 512
    int* tbl    = counts + NDIM;                  // 512*16
    int* perm   = tbl + NDIM * NSLOT;             // 512
    int* scnt   = perm + NDIM;                    // 512
    int* stbl   = scnt + NDIM;                    // 512*16  (~72 KB total)

    const int nrows  = in_sizes[0] / KDIM;        // 65536
    const int ntiles = nrows / ROWS;              // 4096

    build_tbl<<<NDIM, 64, 0, stream>>>(w, counts, tbl);
    sort_cols<<<1, 512, 0, stream>>>(counts, tbl, perm, scnt, stbl);
    ternary_mm<<<1024, 512, 0, stream>>>(x, w, perm, scnt, stbl, out, ntiles);
}